// Round 10
// baseline (265.854 us; speedup 1.0000x reference)
//
#include <hip/hip_runtime.h>

// B=2, S=2048, H=1024, NUM_HEAD=16, HEAD=64
#define BATCH 2
#define S_LEN 2048
#define HDIM  1024
#define NHEAD 16
#define HD    64
#define NEGBIAS -1e10f

typedef __attribute__((ext_vector_type(8)))  _Float16 half8;
typedef __attribute__((ext_vector_type(4)))  _Float16 half4;
typedef __attribute__((ext_vector_type(4)))  float    f32x4;
typedef __attribute__((ext_vector_type(16))) float    f32x16;  // 32x32 MFMA C/D

// ---------------------------------------------------------------------------
// mask -> float bias array (4096 elems), read by flash via VMEM.
// ---------------------------------------------------------------------------
__global__ __launch_bounds__(256) void cvt_bias(const int* __restrict__ mask,
                                                float* __restrict__ biasF)
{
    int i = blockIdx.x * 256 + threadIdx.x;
    biasF[i] = mask[i] ? 0.f : NEGBIAS;
}

// ---------------------------------------------------------------------------
// Fused projection GEMM (fp16 MFMA): Y = X @ W^T + b, register-prefetch
// pipeline.  z=0,1 -> [B,NH,S,HD]; z=2 -> V^T [B,NH,HD,S].
// Epilogue uses half4 stores: for z<2 the MFMA operands are SWAPPED so the
// C-layout register quad runs along d (contiguous); z=2 keeps normal order
// so the quad runs along s (contiguous in V^T).
// ---------------------------------------------------------------------------
__global__ __launch_bounds__(256) void proj_gemm_f16(
    const float* __restrict__ Xq, const float* __restrict__ Wq, const float* __restrict__ bq,
    const float* __restrict__ Xk, const float* __restrict__ Wk, const float* __restrict__ bk,
    const float* __restrict__ Xv, const float* __restrict__ Wv, const float* __restrict__ bv,
    _Float16* __restrict__ Qb, _Float16* __restrict__ Kb, _Float16* __restrict__ Vtb)
{
    const int z = blockIdx.z;
    const float* X    = (z == 0) ? Xq : (z == 1) ? Xk : Xv;
    const float* W    = (z == 0) ? Wq : (z == 1) ? Wk : Wv;
    const float* bias = (z == 0) ? bq : (z == 1) ? bk : bv;
    _Float16* Y       = (z == 0) ? Qb : (z == 1) ? Kb : Vtb;

    const int n0 = blockIdx.x * 128;
    const int m0 = blockIdx.y * 128;

    __shared__ __align__(16) _Float16 As[128][40];
    __shared__ __align__(16) _Float16 Bs[128][40];

    const int t    = threadIdx.x;
    const int w    = t >> 6;
    const int lane = t & 63;
    const int quad = lane >> 4;
    const int lc   = lane & 15;
    const int wm   = (w >> 1) * 64;
    const int wn   = (w & 1) * 64;

    const f32x4 fzero = {0.f, 0.f, 0.f, 0.f};
    f32x4 acc[4][4];
#pragma unroll
    for (int i = 0; i < 4; i++)
#pragma unroll
        for (int j = 0; j < 4; j++) acc[i][j] = fzero;

    const int srow = t >> 2;
    const int sc   = t & 3;

    float4 xa[2][2], wa[2][2];
#define PROJ_ISSUE(K0)                                                        \
    {                                                                         \
        _Pragma("unroll")                                                     \
        for (int hf = 0; hf < 2; hf++) {                                      \
            const float* gx = X + (size_t)(m0 + srow + hf * 64) * HDIM + (K0) + sc * 8; \
            xa[hf][0] = *(const float4*)gx;                                   \
            xa[hf][1] = *(const float4*)(gx + 4);                             \
            const float* gw = W + (size_t)(n0 + srow + hf * 64) * HDIM + (K0) + sc * 8; \
            wa[hf][0] = *(const float4*)gw;                                   \
            wa[hf][1] = *(const float4*)(gw + 4);                             \
        }                                                                     \
    }

    PROJ_ISSUE(0)

    for (int k0 = 0; k0 < HDIM; k0 += 32) {
        if (k0) __syncthreads();
#pragma unroll
        for (int hf = 0; hf < 2; hf++) {
            int row = srow + hf * 64;
            half8 vx;
            vx[0] = (_Float16)xa[hf][0].x; vx[1] = (_Float16)xa[hf][0].y;
            vx[2] = (_Float16)xa[hf][0].z; vx[3] = (_Float16)xa[hf][0].w;
            vx[4] = (_Float16)xa[hf][1].x; vx[5] = (_Float16)xa[hf][1].y;
            vx[6] = (_Float16)xa[hf][1].z; vx[7] = (_Float16)xa[hf][1].w;
            *(half8*)&As[row][sc * 8] = vx;
            half8 vw;
            vw[0] = (_Float16)wa[hf][0].x; vw[1] = (_Float16)wa[hf][0].y;
            vw[2] = (_Float16)wa[hf][0].z; vw[3] = (_Float16)wa[hf][0].w;
            vw[4] = (_Float16)wa[hf][1].x; vw[5] = (_Float16)wa[hf][1].y;
            vw[6] = (_Float16)wa[hf][1].z; vw[7] = (_Float16)wa[hf][1].w;
            *(half8*)&Bs[row][sc * 8] = vw;
        }
        __syncthreads();

        if (k0 + 32 < HDIM) PROJ_ISSUE(k0 + 32)

        half8 af[4], bf[4];
#pragma unroll
        for (int mt = 0; mt < 4; mt++)
            af[mt] = *(const half8*)&As[wm + mt * 16 + lc][quad * 8];
#pragma unroll
        for (int nt = 0; nt < 4; nt++)
            bf[nt] = *(const half8*)&Bs[wn + nt * 16 + lc][quad * 8];
        if (z == 2) {
#pragma unroll
            for (int mt = 0; mt < 4; mt++)
#pragma unroll
                for (int nt = 0; nt < 4; nt++)
                    acc[mt][nt] = __builtin_amdgcn_mfma_f32_16x16x32_f16(
                        af[mt], bf[nt], acc[mt][nt], 0, 0, 0);   // row=m(s), col=n(d)
        } else {
#pragma unroll
            for (int mt = 0; mt < 4; mt++)
#pragma unroll
                for (int nt = 0; nt < 4; nt++)
                    acc[mt][nt] = __builtin_amdgcn_mfma_f32_16x16x32_f16(
                        bf[nt], af[mt], acc[mt][nt], 0, 0, 0);   // row=n(d), col=m(s)
        }
    }

    if (z == 2) {
        // lane owns 4 consecutive s at fixed d -> contiguous half4 in V^T
#pragma unroll
        for (int nt = 0; nt < 4; nt++) {
            const int n = n0 + wn + nt * 16 + lc;           // h*64 + d
            const float bv_ = bias[n];
            const int h = n >> 6, d = n & 63;
#pragma unroll
            for (int mt = 0; mt < 4; mt++) {
                const int m = m0 + wm + mt * 16 + quad * 4;  // 4-run of s
                const int b = m >> 11, s = m & (S_LEN - 1);
                half4 hv;
#pragma unroll
                for (int r = 0; r < 4; r++) hv[r] = (_Float16)(acc[mt][nt][r] + bv_);
                *(half4*)&Y[(((size_t)b * NHEAD + h) * HD + d) * S_LEN + s] = hv;
            }
        }
    } else {
        // lane owns 4 consecutive d at fixed s -> contiguous half4 in Q/K
#pragma unroll
        for (int mt = 0; mt < 4; mt++) {
            const int m = m0 + wm + mt * 16 + lc;            // b*S + s
            const int b = m >> 11, s = m & (S_LEN - 1);
#pragma unroll
            for (int nt = 0; nt < 4; nt++) {
                const int n = n0 + wn + nt * 16 + quad * 4;  // 4-run of d
                const int h = n >> 6, d = n & 63;
                float4 b4 = *(const float4*)&bias[n];
                half4 hv;
                hv[0] = (_Float16)(acc[mt][nt][0] + b4.x);
                hv[1] = (_Float16)(acc[mt][nt][1] + b4.y);
                hv[2] = (_Float16)(acc[mt][nt][2] + b4.z);
                hv[3] = (_Float16)(acc[mt][nt][3] + b4.w);
                *(half4*)&Y[(((size_t)b * NHEAD + h) * S_LEN + s) * HD + d] = hv;
            }
        }
    }
}

// ---------------------------------------------------------------------------
// Flash attention, 32x32x16 MFMA.  Wave = 32 q (q = lane&31), h = lane>>5
// splits keys/dims.  S^T = K.Q^T, O^T = V^T.P^T.  Softmax: in-register
// reduce over 32 + ONE shfl_xor(32) each for max and sum.  Mask bias read
// from precomputed float array via VMEM (no LDS).  K/V register prefetch.
// Block = 128 q (4 waves), grid 512.
// ---------------------------------------------------------------------------
__global__ __launch_bounds__(256) void flash_attn_mfma(
    const _Float16* __restrict__ Qb, const _Float16* __restrict__ Kb,
    const _Float16* __restrict__ Vtb, const float* __restrict__ biasF,
    float* __restrict__ out)
{
    const int qt = blockIdx.x & 15;      // 16 q-tiles of 128
    const int bh = blockIdx.x >> 4;      // 0..31
    const int b  = bh >> 4;
    const int hh = bh & (NHEAD - 1);

    __shared__ __align__(16) _Float16 Ks [64][72];      // [key][d]
    __shared__ __align__(16) _Float16 Vts[64][72];      // [d][key]
    __shared__ __align__(16) _Float16 Ps [4][32][72];   // per-wave P, [q][key]

    const int t    = threadIdx.x;
    const int w    = t >> 6;
    const int lane = t & 63;
    const int h    = lane >> 5;          // key/dim half
    const int l5   = lane & 31;          // q column / m-index

    const _Float16* Kbase = Kb  + (size_t)bh * S_LEN * HD;
    const _Float16* Vbase = Vtb + (size_t)bh * HD * S_LEN;
    const float* bbase = biasF + b * S_LEN;

    // Q B-frags: n = l5 (q), k = ks*16 + h*8 + j
    const int qrow = qt * 128 + w * 32 + l5;
    half8 qf[4];
#pragma unroll
    for (int ks = 0; ks < 4; ks++)
        qf[ks] = *(const half8*)(Qb + ((size_t)bh * S_LEN + qrow) * HD
                                 + ks * 16 + h * 8);

    f32x16 o[2];                        // O^T: d = dt*32 + 8g+4h+r, q = l5
#pragma unroll
    for (int dt = 0; dt < 2; dt++)
#pragma unroll
        for (int r = 0; r < 16; r++) o[dt][r] = 0.f;
    float mrun = -3.0e38f;
    float lrun = 0.f;

    const int rr0 = t >> 3,       cc0 = (t & 7) * 8;
    const int rr1 = rr0 + 32,     cc1 = cc0;

    half8 kpre[2], vpre[2];
#define ATTN_ISSUE(KT)                                                        \
    {                                                                         \
        kpre[0] = *(const half8*)(Kbase + (size_t)((KT) + rr0) * HD + cc0);   \
        kpre[1] = *(const half8*)(Kbase + (size_t)((KT) + rr1) * HD + cc1);   \
        vpre[0] = *(const half8*)(Vbase + (size_t)rr0 * S_LEN + (KT) + cc0);  \
        vpre[1] = *(const half8*)(Vbase + (size_t)rr1 * S_LEN + (KT) + cc1);  \
    }

    ATTN_ISSUE(0)

    for (int kt = 0; kt < S_LEN; kt += 64) {
        if (kt) __syncthreads();
        *(half8*)&Ks [rr0][cc0] = kpre[0];
        *(half8*)&Ks [rr1][cc1] = kpre[1];
        *(half8*)&Vts[rr0][cc0] = vpre[0];
        *(half8*)&Vts[rr1][cc1] = vpre[1];
        __syncthreads();

        if (kt + 64 < S_LEN) ATTN_ISSUE(kt + 64)

        // S^T = K.Q^T : 2 key-tiles x 4 k-steps, 32x32x16
        f32x16 scf[2];
#pragma unroll
        for (int tt = 0; tt < 2; tt++)
#pragma unroll
            for (int r = 0; r < 16; r++) scf[tt][r] = 0.f;
#pragma unroll
        for (int ks = 0; ks < 4; ks++) {
#pragma unroll
            for (int tt = 0; tt < 2; tt++) {
                half8 kf = *(const half8*)&Ks[tt * 32 + l5][ks * 16 + h * 8];
                scf[tt] = __builtin_amdgcn_mfma_f32_32x32x16_f16(kf, qf[ks], scf[tt], 0, 0, 0);
            }
        }

        // mask bias via VMEM float4: reg g*4+r <-> key tt*32 + 8g + 4h + r
#pragma unroll
        for (int tt = 0; tt < 2; tt++)
#pragma unroll
            for (int g = 0; g < 4; g++) {
                float4 b4 = *(const float4*)&bbase[kt + tt * 32 + g * 8 + h * 4];
                scf[tt][g * 4 + 0] += b4.x; scf[tt][g * 4 + 1] += b4.y;
                scf[tt][g * 4 + 2] += b4.z; scf[tt][g * 4 + 3] += b4.w;
            }

        // per-lane online softmax (q = l5; the two h-lanes merge via xor 32)
        float mx = scf[0][0];
#pragma unroll
        for (int tt = 0; tt < 2; tt++)
#pragma unroll
            for (int r = 0; r < 16; r++) mx = fmaxf(mx, scf[tt][r]);
        mx = fmaxf(mx, __shfl_xor(mx, 32));

        float mn = fmaxf(mrun, mx);
        float al = __expf(mrun - mn);
        float ls = 0.f;
#pragma unroll
        for (int tt = 0; tt < 2; tt++)
#pragma unroll
            for (int r = 0; r < 16; r++) {
                float p = __expf(scf[tt][r] - mn);
                scf[tt][r] = p;
                ls += p;
            }
        ls += __shfl_xor(ls, 32);
        lrun = lrun * al + ls;
        mrun = mn;
#pragma unroll
        for (int dt = 0; dt < 2; dt++)
#pragma unroll
            for (int r = 0; r < 16; r++) o[dt][r] *= al;

        // P rows (q-major): Ps[w][l5][key], half4 per (tt,g)
#pragma unroll
        for (int tt = 0; tt < 2; tt++)
#pragma unroll
            for (int g = 0; g < 4; g++) {
                half4 pk;
                pk[0] = (_Float16)scf[tt][g * 4 + 0];
                pk[1] = (_Float16)scf[tt][g * 4 + 1];
                pk[2] = (_Float16)scf[tt][g * 4 + 2];
                pk[3] = (_Float16)scf[tt][g * 4 + 3];
                *(half4*)&Ps[w][l5][tt * 32 + g * 8 + h * 4] = pk;
            }

        // O^T += V^T.P^T : A = Vt-frag (m=d), B = P^T-frag (n=q)
#pragma unroll
        for (int ks = 0; ks < 4; ks++) {
            half8 pf = *(const half8*)&Ps[w][l5][ks * 16 + h * 8];
#pragma unroll
            for (int dt = 0; dt < 2; dt++) {
                half8 vf = *(const half8*)&Vts[dt * 32 + l5][ks * 16 + h * 8];
                o[dt] = __builtin_amdgcn_mfma_f32_32x32x16_f16(vf, pf, o[dt], 0, 0, 0);
            }
        }
    }

    // epilogue: lane owns q-row qrow; d runs 8g+4h -> float4 stores
    const float inv = 1.f / lrun;
    const size_t rowb = ((size_t)b * S_LEN + qrow) * HDIM + hh * HD;
#pragma unroll
    for (int dt = 0; dt < 2; dt++)
#pragma unroll
        for (int g = 0; g < 4; g++) {
            float4 v;
            v.x = o[dt][g * 4 + 0] * inv; v.y = o[dt][g * 4 + 1] * inv;
            v.z = o[dt][g * 4 + 2] * inv; v.w = o[dt][g * 4 + 3] * inv;
            *(float4*)&out[rowb + dt * 32 + g * 8 + h * 4] = v;
        }
}

// ---------------------------------------------------------------------------
extern "C" void kernel_launch(void* const* d_in, const int* in_sizes, int n_in,
                              void* d_out, int out_size, void* d_ws, size_t ws_size,
                              hipStream_t stream) {
    const float* query = (const float*)d_in[0];
    const float* key   = (const float*)d_in[1];
    const float* value = (const float*)d_in[2];
    const int*   mask  = (const int*)  d_in[3];
    const float* Wq    = (const float*)d_in[4];
    const float* bq    = (const float*)d_in[5];
    const float* Wk    = (const float*)d_in[6];
    const float* bk    = (const float*)d_in[7];
    const float* Wv    = (const float*)d_in[8];
    const float* bv    = (const float*)d_in[9];
    float* out = (float*)d_out;

    const size_t nElem = (size_t)BATCH * S_LEN * HDIM;          // 4M
    const size_t need = 3 * nElem * sizeof(_Float16)
                      + (size_t)BATCH * S_LEN * sizeof(float);  // 24MB + 16KB
    if (ws_size < need) return;
    _Float16* Qb    = (_Float16*)d_ws;
    _Float16* Kb    = Qb + nElem;
    _Float16* Vtb   = Kb + nElem;
    float*    biasF = (float*)(Vtb + nElem);

    cvt_bias<<<(BATCH * S_LEN) / 256, 256, 0, stream>>>(mask, biasF);

    dim3 gproj(HDIM / 128, (BATCH * S_LEN) / 128, 3);           // (8, 32, 3)
    proj_gemm_f16<<<gproj, 256, 0, stream>>>(query, Wq, bq, key, Wk, bk,
                                             value, Wv, bv, Qb, Kb, Vtb);

    flash_attn_mfma<<<BATCH * NHEAD * (S_LEN / 128), 256, 0, stream>>>(
        Qb, Kb, Vtb, biasF, out);
}